// Round 1
// 327.448 us; speedup vs baseline: 1.0540x; 1.0540x over previous
//
#include <hip/hip_runtime.h>
#include <hip/hip_bf16.h>

// Problem constants
#define T_DIM 2048
#define B_DIM 8
#define D_DIM 1024
#define M_DIM (T_DIM * B_DIM)     // 16384
#define K_DIM D_DIM               // 1024
#define NW_DIM (2 * D_DIM)        // 2048 combined GEMM cols (alpha | v)
#define NCH (B_DIM * D_DIM)       // 8192 channels
#define NCH4 (NCH / 4)            // 2048 float4 channels
#define CHUNKS 64
#define CHUNK_LEN 32              // 64*32 = 2048 = T

typedef __attribute__((ext_vector_type(8))) short bf16x8;
typedef __attribute__((ext_vector_type(4))) float f32x4;

__device__ __forceinline__ unsigned short bf16_rne(float f) {
    unsigned u = __float_as_uint(f);
    unsigned r = u + 0x7fffu + ((u >> 16) & 1u);
    return (unsigned short)(r >> 16);
}

__device__ __forceinline__ float sigmoidf(float z) {
    return 1.0f / (1.0f + __expf(-z));
}

__device__ __forceinline__ void load_lds16(const void* g, void* l) {
    __builtin_amdgcn_global_load_lds(
        (const __attribute__((address_space(1))) void*)g,
        (__attribute__((address_space(3))) void*)l,
        16, 0, 0);
}

// ---------------- fp32 -> bf16 convert (x) ----------------
__global__ void f32_to_bf16_kernel(const float4* __restrict__ in,
                                   ushort4* __restrict__ out, int n4) {
    int i = blockIdx.x * blockDim.x + threadIdx.x;
    if (i < n4) {
        float4 f = in[i];
        ushort4 o;
        o.x = bf16_rne(f.x);
        o.y = bf16_rne(f.y);
        o.z = bf16_rne(f.z);
        o.w = bf16_rne(f.w);
        out[i] = o;
    }
}

// ---------------- weights convert: Wcat = [Wa ; Wv] bf16 ----------------
__global__ void conv_weights_kernel(const float4* __restrict__ Wa,
                                    const float4* __restrict__ Wv,
                                    ushort4* __restrict__ Wcat) {
    const int half4 = D_DIM * D_DIM / 4;  // 262144
    int i = blockIdx.x * blockDim.x + threadIdx.x;  // 0 .. 2*half4-1
    float4 f = (i < half4) ? Wa[i] : Wv[i - half4];
    ushort4 o;
    o.x = bf16_rne(f.x);
    o.y = bf16_rne(f.y);
    o.z = bf16_rne(f.z);
    o.w = bf16_rne(f.w);
    Wcat[i] = o;
}

// ---------------- fused bf16 MFMA GEMM, 256x256 deep-pipelined ----------
// A: [M,K] bf16 row-major.  Wcat: [2048,1024] bf16 row-major (B^T layout).
// cols [0,1024): alpha = sigmoid(xWa^T + ba) -> alpha_dst
// cols [1024,2048): v = xWv^T + bv -> v_dst. Both dsts row stride 1024.
//
// Schedule (T2+T3+T4+T5 stack, plain HIP):
//  - 256x256 block tile, 512 threads = 8 waves in 2(M)x4(N); wave = 128x64.
//  - BK=32 K-tiles in a RING OF 4 LDS buffers (4 x (A 16K + B 16K) = 128 KiB),
//    staged 2 K-tiles ahead via global_load_lds width=16.
//  - Counted s_waitcnt vmcnt(4) once per K-tile — never 0 in the main loop —
//    so the 4 newest loads stay in flight across raw s_barrier.
//  - 2 phases per K-tile: {ds_read frags | issue 2 gload_lds | barrier |
//    lgkmcnt(0) | setprio(1) | 16 MFMA | setprio(0) | barrier}.
//  - LDS XOR swizzle: 128 B physical rows hold 2 tile rows; 16B-block
//    perm p = (((r&1)<<2)|q) ^ ((r>>1)&7). Inverse perm applied to the
//    GLOBAL source (gload_lds dest must stay linear). ds_read_b128 lands
//    at the uniform 8-access/bank floor (2-way/beat = free).
//  - Bijective XCD swizzle over the 512-block grid (512 % 8 == 0).
#define MMA_QUAD(IB)                                                        \
    _Pragma("unroll") for (int i = 0; i < 4; ++i)                           \
    _Pragma("unroll") for (int j = 0; j < 4; ++j)                           \
        acc[(IB) + i][j] = __builtin_amdgcn_mfma_f32_16x16x32_bf16(         \
            af[i], bf[j], acc[(IB) + i][j], 0, 0, 0);

__global__ __launch_bounds__(512, 2) void gemm_fused_kernel(
    const unsigned short* __restrict__ A,
    const unsigned short* __restrict__ W,
    const float* __restrict__ ba,
    const float* __restrict__ bv,
    float* __restrict__ alpha_dst,
    float* __restrict__ v_dst) {
    extern __shared__ __attribute__((aligned(16))) char smem[];

    const int tid = threadIdx.x;
    const int lane = tid & 63;
    const int w = tid >> 6;          // wave 0..7
    const int wm = w >> 2;           // wave row (0..1) -> 128 rows each
    const int wn = w & 3;            // wave col (0..3) -> 64 cols each
    const int quad = lane >> 4;      // 0..3
    const int l16 = lane & 15;

    // XCD-aware bijective swizzle: nwg=512, 64 blocks per XCD chunk.
    const int bid = blockIdx.x;
    const int swz = (bid & 7) * 64 + (bid >> 3);
    const int bx = swz & 7;          // N tile (0..7)
    const int by = swz >> 3;         // M tile (0..63)
    const int bm = by * 256;
    const int bn = bx * 256;         // col in the 2048-wide space

    // --- fragment-read byte offsets (swizzled LDS) ---
    // logical (r,q): r = wm*128 + i*16 + l16, q = quad (8 bf16 at k=q*8)
    // phys byte = (r>>1)*128 + ((((r&1)<<2)|q) ^ (r>>1 & 7))*16
    const int vsw = (((l16 & 1) << 2) | quad) ^ (l16 >> 1);
    const int rdA = wm * 8192 + (l16 >> 1) * 128 + vsw * 16;  // + i*1024
    const int rdB = wn * 4096 + (l16 >> 1) * 128 + vsw * 16;  // + j*1024

    // --- staging source offsets (inverse swizzle on global address) ---
    // instruction (2w+j) fills LDS bytes [(2w+j)*1024, +1024): lds-rows
    // h = 8*(2w+j)+ (lane>>3), block p = lane&7. Source logical:
    // v' = p ^ (h&7); r = 2h + (v'>>2); q = v'&3.
    const int p = lane & 7;
    const int hl = lane >> 3;            // 0..7  (== h&7)
    const int vp = p ^ hl;
    const int qsrc = vp & 3;
    const int rb = (vp >> 2) & 1;
    const int r0 = 16 * (2 * w + 0) + 2 * hl + rb;   // tile row, load 0
    const int r1 = 16 * (2 * w + 1) + 2 * hl + rb;   // tile row, load 1
    const char* Ab = (const char*)A;
    const char* Wb = (const char*)W;
    const size_t offA0 = (size_t)(bm + r0) * 2048 + (size_t)qsrc * 16;
    const size_t offA1 = (size_t)(bm + r1) * 2048 + (size_t)qsrc * 16;
    const size_t offB0 = (size_t)(bn + r0) * 2048 + (size_t)qsrc * 16;
    const size_t offB1 = (size_t)(bn + r1) * 2048 + (size_t)qsrc * 16;
    const int lds0 = (2 * w + 0) * 1024;   // wave-uniform dests
    const int lds1 = (2 * w + 1) * 1024;

    f32x4 acc[8][4];
    bf16x8 af[4], bf[4];
    {
        f32x4 zero = {0.f, 0.f, 0.f, 0.f};
#pragma unroll
        for (int i = 0; i < 8; ++i)
#pragma unroll
            for (int j = 0; j < 4; ++j) acc[i][j] = zero;
    }

    auto stage_a = [&](int buf, int ts) {
        char* base = smem + (buf << 15);
        load_lds16(Ab + offA0 + (size_t)ts * 64, base + lds0);
        load_lds16(Ab + offA1 + (size_t)ts * 64, base + lds1);
    };
    auto stage_b = [&](int buf, int ts) {
        char* base = smem + (buf << 15) + 16384;
        load_lds16(Wb + offB0 + (size_t)ts * 64, base + lds0);
        load_lds16(Wb + offB1 + (size_t)ts * 64, base + lds1);
    };
    auto read_a = [&](int buf, int ib) {
        const char* la = smem + (buf << 15);
#pragma unroll
        for (int i = 0; i < 4; ++i)
            af[i] = *(const bf16x8*)(la + rdA + (ib + i) * 1024);
    };
    auto read_b = [&](int buf) {
        const char* lb = smem + (buf << 15) + 16384;
#pragma unroll
        for (int j = 0; j < 4; ++j)
            bf[j] = *(const bf16x8*)(lb + rdB + j * 1024);
    };

    // Phase A of K-tile t: A rows 0..63 (frags 0..3) x all B cols; stages
    // the A half of K-tile t+2 into ring slot (t+2)&3.
    auto phaseA = [&](int t, bool do_stage) {
        const int buf = t & 3;
        read_a(buf, 0);
        read_b(buf);
        if (do_stage) stage_a((t + 2) & 3, t + 2);
        __builtin_amdgcn_s_barrier();
        asm volatile("s_waitcnt lgkmcnt(0)" ::: "memory");
        __builtin_amdgcn_sched_barrier(0);
        __builtin_amdgcn_s_setprio(1);
        MMA_QUAD(0)
        __builtin_amdgcn_s_setprio(0);
        __builtin_amdgcn_s_barrier();
    };
    // Phase B: A rows 64..127 (frags 4..7); stages B half of t+2; counted
    // vmcnt(4) leaves t+2's 4 loads in flight, guarantees t+1 landed.
    auto phaseB = [&](int t, bool do_stage, int vm) {
        const int buf = t & 3;
        read_a(buf, 4);
        if (do_stage) stage_b((t + 2) & 3, t + 2);
        if (vm == 4) asm volatile("s_waitcnt vmcnt(4)" ::: "memory");
        else if (vm == 0) asm volatile("s_waitcnt vmcnt(0)" ::: "memory");
        __builtin_amdgcn_s_barrier();
        asm volatile("s_waitcnt lgkmcnt(0)" ::: "memory");
        __builtin_amdgcn_sched_barrier(0);
        __builtin_amdgcn_s_setprio(1);
        MMA_QUAD(4)
        __builtin_amdgcn_s_setprio(0);
        __builtin_amdgcn_s_barrier();
    };

    // prologue: stage K-tiles 0 and 1; wait tile 0 (leave tile 1 in flight)
    stage_a(0, 0); stage_b(0, 0);
    stage_a(1, 1); stage_b(1, 1);
    asm volatile("s_waitcnt vmcnt(4)" ::: "memory");
    __builtin_amdgcn_s_barrier();

    // 32 K-tiles total (K=1024, BK=32). Main loop stages tiles 2..31.
    for (int t = 0; t < 30; ++t) {
        phaseA(t, true);
        phaseB(t, true, 4);
    }
    phaseA(30, false);
    phaseB(30, false, 0);    // drain: tile 31 must land (last wait)
    phaseA(31, false);
    phaseB(31, false, -1);

    // epilogue: C/D layout col = lane&15, row = quad*4 + reg.
    // bn multiples of 256 -> tile entirely alpha or v (block-uniform).
    const bool is_alpha = (bn < D_DIM);
    float* __restrict__ dst = is_alpha ? alpha_dst : v_dst;
    const float* __restrict__ bias = is_alpha ? ba : bv;
    const int nb = bn - (is_alpha ? 0 : D_DIM);
#pragma unroll
    for (int j = 0; j < 4; ++j) {
        const int n = nb + wn * 64 + j * 16 + l16;
        const float bias_n = bias[n];
#pragma unroll
        for (int i = 0; i < 8; ++i) {
            const int m0 = bm + wm * 128 + i * 16 + quad * 4;
#pragma unroll
            for (int r = 0; r < 4; ++r) {
                float val = acc[i][j][r] + bias_n;
                if (is_alpha) val = sigmoidf(val);
                dst[(size_t)(m0 + r) * D_DIM + n] = val;
            }
        }
    }
}

// ---------------- chunked parallel scan ----------------
// h_t = a_t*h_{t-1} + (1-a_t)*v_t  == affine h_out = P*h_in + Q per chunk.

// Phase 1: per (chunk, channel4) compute chunk composition (P,Q).
__global__ __launch_bounds__(256) void scan_phase1_kernel(
    const float4* __restrict__ alpha,  // [T][NCH4]
    const float4* __restrict__ v,      // [T][NCH4]
    float4* __restrict__ P,            // [CHUNKS][NCH4]
    float4* __restrict__ Q) {
    const int j4 = blockIdx.x * 256 + threadIdx.x;  // 0..NCH4-1
    const int c = blockIdx.y;
    float4 Pr = {1.f, 1.f, 1.f, 1.f};
    float4 Qr = {0.f, 0.f, 0.f, 0.f};
    size_t base = (size_t)c * CHUNK_LEN * NCH4 + j4;
#pragma unroll 4
    for (int t = 0; t < CHUNK_LEN; ++t) {
        float4 a = alpha[base + (size_t)t * NCH4];
        float4 vv = v[base + (size_t)t * NCH4];
        Pr.x *= a.x; Pr.y *= a.y; Pr.z *= a.z; Pr.w *= a.w;
        Qr.x = a.x * Qr.x + (1.f - a.x) * vv.x;
        Qr.y = a.y * Qr.y + (1.f - a.y) * vv.y;
        Qr.z = a.z * Qr.z + (1.f - a.z) * vv.z;
        Qr.w = a.w * Qr.w + (1.f - a.w) * vv.w;
    }
    P[(size_t)c * NCH4 + j4] = Pr;
    Q[(size_t)c * NCH4 + j4] = Qr;
}

// Phase 2: exclusive prefix over chunks (2048 threads, 64 sequential steps).
__global__ __launch_bounds__(256) void scan_phase2_kernel(
    const float4* __restrict__ P, const float4* __restrict__ Q,
    const float4* __restrict__ h0,  // [NCH4]
    float4* __restrict__ Hc) {      // [CHUNKS][NCH4] = h at chunk start
    const int j4 = blockIdx.x * 256 + threadIdx.x;
    float4 h = h0[j4];
#pragma unroll 8
    for (int c = 0; c < CHUNKS; ++c) {
        Hc[(size_t)c * NCH4 + j4] = h;
        float4 p = P[(size_t)c * NCH4 + j4];
        float4 q = Q[(size_t)c * NCH4 + j4];
        h.x = p.x * h.x + q.x;
        h.y = p.y * h.y + q.y;
        h.z = p.z * h.z + q.z;
        h.w = p.w * h.w + q.w;
    }
}

// Phase 3: replay chunk with correct incoming h; in-place overwrite:
// alpha region -> output, v region -> h[t+1].
__global__ __launch_bounds__(256) void scan_phase3_kernel(
    float4* __restrict__ alpha_out,  // in: alpha[t], out: output[t]
    float4* __restrict__ v_h,        // in: v[t] (at h[t+1] slot), out: h[t+1]
    const float4* __restrict__ Hc) {
    const int j4 = blockIdx.x * 256 + threadIdx.x;
    const int c = blockIdx.y;
    float4 h = Hc[(size_t)c * NCH4 + j4];
    size_t base = (size_t)c * CHUNK_LEN * NCH4 + j4;
#pragma unroll 4
    for (int t = 0; t < CHUNK_LEN; ++t) {
        float4 a = alpha_out[base + (size_t)t * NCH4];
        float4 vv = v_h[base + (size_t)t * NCH4];
        h.x = a.x * h.x + (1.f - a.x) * vv.x;
        h.y = a.y * h.y + (1.f - a.y) * vv.y;
        h.z = a.z * h.z + (1.f - a.z) * vv.z;
        h.w = a.w * h.w + (1.f - a.w) * vv.w;
        float4 o;
        o.x = h.x * h.x * sigmoidf(h.x);
        o.y = h.y * h.y * sigmoidf(h.y);
        o.z = h.z * h.z * sigmoidf(h.z);
        o.w = h.w * h.w * sigmoidf(h.w);
        alpha_out[base + (size_t)t * NCH4] = o;
        v_h[base + (size_t)t * NCH4] = h;
    }
}

extern "C" void kernel_launch(void* const* d_in, const int* in_sizes, int n_in,
                              void* d_out, int out_size, void* d_ws, size_t ws_size,
                              hipStream_t stream) {
    const float* x  = (const float*)d_in[0];   // [T,B,D]
    const float* h0 = (const float*)d_in[1];   // [B,D]
    const float* Wa = (const float*)d_in[2];   // [D,D]
    const float* ba = (const float*)d_in[3];   // [D]
    const float* Wv = (const float*)d_in[4];   // [D,D]
    const float* bv = (const float*)d_in[5];   // [D]

    float* out = (float*)d_out;                       // output region [T][NCH]
    float* hbase = out + (size_t)T_DIM * NCH;         // h region [T+1][NCH]
    float* alpha = out;                               // temp alpha in output region
    float* vbuf = hbase + NCH;                        // temp v in h[1..T]

    char* ws = (char*)d_ws;
    unsigned short* xb   = (unsigned short*)ws;                      // 32 MB
    unsigned short* Wcat = (unsigned short*)(ws + 33554432);         // 4 MB
    float* P  = (float*)(ws + 37748736);                             // 2 MB
    float* Q  = (float*)(ws + 39845888);                             // 2 MB
    float* Hc = (float*)(ws + 41943040);                             // 2 MB

    // one-time: allow 128 KiB dynamic LDS for the GEMM
    static bool attr_done = false;
    if (!attr_done) {
        hipFuncSetAttribute(reinterpret_cast<const void*>(gemm_fused_kernel),
                            hipFuncAttributeMaxDynamicSharedMemorySize, 131072);
        attr_done = true;
    }

    // 1. convert inputs to bf16
    f32_to_bf16_kernel<<<(M_DIM * K_DIM / 4) / 256, 256, 0, stream>>>(
        (const float4*)x, (ushort4*)xb, M_DIM * K_DIM / 4);
    conv_weights_kernel<<<(2 * D_DIM * D_DIM / 4) / 256, 256, 0, stream>>>(
        (const float4*)Wa, (const float4*)Wv, (ushort4*)Wcat);

    // 2. fused GEMM: alpha = sigmoid(x Wa^T + ba) -> output region
    //                v     =         x Wv^T + bv  -> h[1..T] region
    gemm_fused_kernel<<<512, 512, 131072, stream>>>(xb, Wcat, ba, bv, alpha, vbuf);

    // 3. h[0] = h0
    hipMemcpyAsync(hbase, h0, (size_t)NCH * sizeof(float),
                   hipMemcpyDeviceToDevice, stream);

    // 4. chunked scan
    dim3 sgrid(NCH4 / 256, CHUNKS);
    scan_phase1_kernel<<<sgrid, 256, 0, stream>>>(
        (const float4*)alpha, (const float4*)vbuf, (float4*)P, (float4*)Q);
    scan_phase2_kernel<<<NCH4 / 256, 256, 0, stream>>>(
        (const float4*)P, (const float4*)Q, (const float4*)h0, (float4*)Hc);
    scan_phase3_kernel<<<sgrid, 256, 0, stream>>>(
        (float4*)alpha, (float4*)vbuf, (const float4*)Hc);
}

// Round 2
// 320.764 us; speedup vs baseline: 1.0759x; 1.0208x over previous
//
#include <hip/hip_runtime.h>
#include <hip/hip_bf16.h>

// Problem constants
#define T_DIM 2048
#define B_DIM 8
#define D_DIM 1024
#define M_DIM (T_DIM * B_DIM)     // 16384
#define K_DIM D_DIM               // 1024
#define NW_DIM (2 * D_DIM)        // 2048 combined GEMM cols (alpha | v)
#define NCH (B_DIM * D_DIM)       // 8192 channels
#define NCH4 (NCH / 4)            // 2048 float4 channels
#define CHUNKS 64
#define CHUNK_LEN 32              // 64*32 = 2048 = T

typedef __attribute__((ext_vector_type(8))) short bf16x8;
typedef __attribute__((ext_vector_type(4))) float f32x4;

__device__ __forceinline__ unsigned short bf16_rne(float f) {
    unsigned u = __float_as_uint(f);
    unsigned r = u + 0x7fffu + ((u >> 16) & 1u);
    return (unsigned short)(r >> 16);
}

__device__ __forceinline__ float sigmoidf(float z) {
    return 1.0f / (1.0f + __expf(-z));
}

__device__ __forceinline__ void load_lds16(const void* g, void* l) {
    __builtin_amdgcn_global_load_lds(
        (const __attribute__((address_space(1))) void*)g,
        (__attribute__((address_space(3))) void*)l,
        16, 0, 0);
}

// ---------------- fused input conversion: x, Wa, Wv -> bf16 ----------------
// one kernel = one launch; covers x (4194304 float4) then Wcat (524288).
__global__ __launch_bounds__(256) void convert_all_kernel(
    const float4* __restrict__ x,
    const float4* __restrict__ Wa,
    const float4* __restrict__ Wv,
    ushort4* __restrict__ xb,
    ushort4* __restrict__ Wcat) {
    const int nx4 = M_DIM * K_DIM / 4;       // 4194304
    const int half4 = D_DIM * D_DIM / 4;     // 262144
    int i = blockIdx.x * 256 + threadIdx.x;
    float4 f;
    ushort4* __restrict__ dst;
    int di;
    if (i < nx4) {
        f = x[i];
        dst = xb;
        di = i;
    } else {
        int j = i - nx4;
        f = (j < half4) ? Wa[j] : Wv[j - half4];
        dst = Wcat;
        di = j;
    }
    ushort4 o;
    o.x = bf16_rne(f.x);
    o.y = bf16_rne(f.y);
    o.z = bf16_rne(f.z);
    o.w = bf16_rne(f.w);
    dst[di] = o;
}

// ---------------- fused bf16 MFMA GEMM, 256x256 deep-pipelined ----------
// A: [M,K] bf16 row-major.  Wcat: [2048,1024] bf16 row-major (B^T layout).
// cols [0,1024): alpha = sigmoid(xWa^T + ba) -> alpha_dst
// cols [1024,2048): v = xWv^T + bv -> v_dst. Both dsts row stride 1024.
//
// Schedule:
//  - 256x256 block tile, 512 threads = 8 waves in 2(M)x4(N); wave = 128x64.
//  - BK=32 K-tiles, RING OF 4 LDS buffers (128 KiB), DEPTH-3 prefetch:
//    tile t+3 staged while computing t; ring holds exactly t..t+3.
//  - Counted s_waitcnt vmcnt(8) once per K-tile (retires tile t+1's 4 loads,
//    leaves t+2/t+3's 8 in flight). Coverage = ~3 K-tiles > HBM latency.
//  - ONE barrier per phase (end only). Pre-MFMA barrier removed: the WAR on
//    ring slot (t+3)&3 == (t-1)&3 is already closed by the end-of-phase
//    barrier of tile t-1 (reads complete before each wave's lgkmcnt(0)).
//    Sub-phase wave skew is desired: one wave's ds_reads overlap another's
//    MFMA on the same SIMD.
//  - LDS XOR swizzle: 128 B physical rows hold 2 tile rows; 16B-block
//    perm p = (((r&1)<<2)|q) ^ ((r>>1)&7). Inverse perm applied to the
//    GLOBAL source (gload_lds dest must stay linear). Measured 0 conflicts.
//  - Bijective XCD swizzle over the 512-block grid (512 % 8 == 0).
#define MMA_QUAD(IB)                                                        \
    _Pragma("unroll") for (int i = 0; i < 4; ++i)                           \
    _Pragma("unroll") for (int j = 0; j < 4; ++j)                           \
        acc[(IB) + i][j] = __builtin_amdgcn_mfma_f32_16x16x32_bf16(         \
            af[i], bf[j], acc[(IB) + i][j], 0, 0, 0);

__global__ __launch_bounds__(512, 2) void gemm_fused_kernel(
    const unsigned short* __restrict__ A,
    const unsigned short* __restrict__ W,
    const float* __restrict__ ba,
    const float* __restrict__ bv,
    float* __restrict__ alpha_dst,
    float* __restrict__ v_dst) {
    extern __shared__ __attribute__((aligned(16))) char smem[];

    const int tid = threadIdx.x;
    const int lane = tid & 63;
    const int w = tid >> 6;          // wave 0..7
    const int wm = w >> 2;           // wave row (0..1) -> 128 rows each
    const int wn = w & 3;            // wave col (0..3) -> 64 cols each
    const int quad = lane >> 4;      // 0..3
    const int l16 = lane & 15;

    // XCD-aware bijective swizzle: nwg=512, 64 blocks per XCD chunk.
    const int bid = blockIdx.x;
    const int swz = (bid & 7) * 64 + (bid >> 3);
    const int bx = swz & 7;          // N tile (0..7)
    const int by = swz >> 3;         // M tile (0..63)
    const int bm = by * 256;
    const int bn = bx * 256;         // col in the 2048-wide space

    // --- fragment-read byte offsets (swizzled LDS) ---
    // logical (r,q): r = wm*128 + i*16 + l16, q = quad (8 bf16 at k=q*8)
    // phys byte = (r>>1)*128 + ((((r&1)<<2)|q) ^ (r>>1 & 7))*16
    const int vsw = (((l16 & 1) << 2) | quad) ^ (l16 >> 1);
    const int rdA = wm * 8192 + (l16 >> 1) * 128 + vsw * 16;  // + i*1024
    const int rdB = wn * 4096 + (l16 >> 1) * 128 + vsw * 16;  // + j*1024

    // --- staging source offsets (inverse swizzle on global address) ---
    // instruction (2w+j) fills LDS bytes [(2w+j)*1024, +1024): lds-rows
    // h = 8*(2w+j)+ (lane>>3), block p = lane&7. Source logical:
    // v' = p ^ (h&7); r = 2h + (v'>>2); q = v'&3.
    const int p = lane & 7;
    const int hl = lane >> 3;            // 0..7  (== h&7)
    const int vp = p ^ hl;
    const int qsrc = vp & 3;
    const int rb = (vp >> 2) & 1;
    const int r0 = 16 * (2 * w + 0) + 2 * hl + rb;   // tile row, load 0
    const int r1 = 16 * (2 * w + 1) + 2 * hl + rb;   // tile row, load 1
    const char* Ab = (const char*)A;
    const char* Wb = (const char*)W;
    const size_t offA0 = (size_t)(bm + r0) * 2048 + (size_t)qsrc * 16;
    const size_t offA1 = (size_t)(bm + r1) * 2048 + (size_t)qsrc * 16;
    const size_t offB0 = (size_t)(bn + r0) * 2048 + (size_t)qsrc * 16;
    const size_t offB1 = (size_t)(bn + r1) * 2048 + (size_t)qsrc * 16;
    const int lds0 = (2 * w + 0) * 1024;   // wave-uniform dests
    const int lds1 = (2 * w + 1) * 1024;

    f32x4 acc[8][4];
    bf16x8 af[4], bf[4];
    {
        f32x4 zero = {0.f, 0.f, 0.f, 0.f};
#pragma unroll
        for (int i = 0; i < 8; ++i)
#pragma unroll
            for (int j = 0; j < 4; ++j) acc[i][j] = zero;
    }

    auto stage_a = [&](int buf, int ts) {
        char* base = smem + (buf << 15);
        load_lds16(Ab + offA0 + (size_t)ts * 64, base + lds0);
        load_lds16(Ab + offA1 + (size_t)ts * 64, base + lds1);
    };
    auto stage_b = [&](int buf, int ts) {
        char* base = smem + (buf << 15) + 16384;
        load_lds16(Wb + offB0 + (size_t)ts * 64, base + lds0);
        load_lds16(Wb + offB1 + (size_t)ts * 64, base + lds1);
    };
    auto read_a = [&](int buf, int ib) {
        const char* la = smem + (buf << 15);
#pragma unroll
        for (int i = 0; i < 4; ++i)
            af[i] = *(const bf16x8*)(la + rdA + (ib + i) * 1024);
    };
    auto read_b = [&](int buf) {
        const char* lb = smem + (buf << 15) + 16384;
#pragma unroll
        for (int j = 0; j < 4; ++j)
            bf[j] = *(const bf16x8*)(lb + rdB + j * 1024);
    };

    // Phase A of K-tile t: A rows 0..63 (frags 0..3) x all B cols; stages
    // the A half of K-tile t+3 into ring slot (t+3)&3.
    auto phaseA = [&](int t, bool do_stage) {
        const int buf = t & 3;
        read_a(buf, 0);
        read_b(buf);
        if (do_stage) stage_a((t + 3) & 3, t + 3);
        asm volatile("s_waitcnt lgkmcnt(0)" ::: "memory");
        __builtin_amdgcn_sched_barrier(0);
        __builtin_amdgcn_s_setprio(1);
        MMA_QUAD(0)
        __builtin_amdgcn_s_setprio(0);
        __builtin_amdgcn_s_barrier();
    };
    // Phase B: A rows 64..127 (frags 4..7); stages B half of t+3; counted
    // vmcnt(8) retires tile t+1's 4 loads, leaves t+2/t+3's in flight.
    auto phaseB = [&](int t, bool do_stage, int vm) {
        const int buf = t & 3;
        read_a(buf, 4);
        if (do_stage) stage_b((t + 3) & 3, t + 3);
        if (vm == 8) asm volatile("s_waitcnt vmcnt(8)" ::: "memory");
        else if (vm == 4) asm volatile("s_waitcnt vmcnt(4)" ::: "memory");
        else if (vm == 0) asm volatile("s_waitcnt vmcnt(0)" ::: "memory");
        asm volatile("s_waitcnt lgkmcnt(0)" ::: "memory");
        __builtin_amdgcn_sched_barrier(0);
        __builtin_amdgcn_s_setprio(1);
        MMA_QUAD(4)
        __builtin_amdgcn_s_setprio(0);
        __builtin_amdgcn_s_barrier();
    };

    // prologue: stage K-tiles 0,1,2 (12 loads); wait tile 0 (vmcnt(8)),
    // leaving tiles 1,2 in flight.
    stage_a(0, 0); stage_b(0, 0);
    stage_a(1, 1); stage_b(1, 1);
    stage_a(2, 2); stage_b(2, 2);
    asm volatile("s_waitcnt vmcnt(8)" ::: "memory");
    __builtin_amdgcn_s_barrier();

    // 32 K-tiles total (K=1024, BK=32). Main loop stages tiles 3..31.
    for (int t = 0; t < 29; ++t) {
        phaseA(t, true);
        phaseB(t, true, 8);
    }
    phaseA(29, false);
    phaseB(29, false, 4);    // retire tile 30's loads (31's stay in flight)
    phaseA(30, false);
    phaseB(30, false, 0);    // drain: tile 31 must land
    phaseA(31, false);
    phaseB(31, false, -1);

    // epilogue: C/D layout col = lane&15, row = quad*4 + reg.
    // bn multiples of 256 -> tile entirely alpha or v (block-uniform).
    const bool is_alpha = (bn < D_DIM);
    float* __restrict__ dst = is_alpha ? alpha_dst : v_dst;
    const float* __restrict__ bias = is_alpha ? ba : bv;
    const int nb = bn - (is_alpha ? 0 : D_DIM);
#pragma unroll
    for (int j = 0; j < 4; ++j) {
        const int n = nb + wn * 64 + j * 16 + l16;
        const float bias_n = bias[n];
#pragma unroll
        for (int i = 0; i < 8; ++i) {
            const int m0 = bm + wm * 128 + i * 16 + quad * 4;
#pragma unroll
            for (int r = 0; r < 4; ++r) {
                float val = acc[i][j][r] + bias_n;
                if (is_alpha) val = sigmoidf(val);
                dst[(size_t)(m0 + r) * D_DIM + n] = val;
            }
        }
    }
}

// ---------------- chunked parallel scan ----------------
// h_t = a_t*h_{t-1} + (1-a_t)*v_t  == affine h_out = P*h_in + Q per chunk.

// Phase 1: per (chunk, channel4) compute chunk composition (P,Q).
__global__ __launch_bounds__(256) void scan_phase1_kernel(
    const float4* __restrict__ alpha,  // [T][NCH4]
    const float4* __restrict__ v,      // [T][NCH4]
    float4* __restrict__ P,            // [CHUNKS][NCH4]
    float4* __restrict__ Q) {
    const int j4 = blockIdx.x * 256 + threadIdx.x;  // 0..NCH4-1
    const int c = blockIdx.y;
    float4 Pr = {1.f, 1.f, 1.f, 1.f};
    float4 Qr = {0.f, 0.f, 0.f, 0.f};
    size_t base = (size_t)c * CHUNK_LEN * NCH4 + j4;
#pragma unroll 4
    for (int t = 0; t < CHUNK_LEN; ++t) {
        float4 a = alpha[base + (size_t)t * NCH4];
        float4 vv = v[base + (size_t)t * NCH4];
        Pr.x *= a.x; Pr.y *= a.y; Pr.z *= a.z; Pr.w *= a.w;
        Qr.x = a.x * Qr.x + (1.f - a.x) * vv.x;
        Qr.y = a.y * Qr.y + (1.f - a.y) * vv.y;
        Qr.z = a.z * Qr.z + (1.f - a.z) * vv.z;
        Qr.w = a.w * Qr.w + (1.f - a.w) * vv.w;
    }
    P[(size_t)c * NCH4 + j4] = Pr;
    Q[(size_t)c * NCH4 + j4] = Qr;
}

// Phase 2: exclusive prefix over chunks. Scalar per channel: 8192 threads
// = 32 blocks (4x the wave count of the old float4 version; this kernel is
// latency-bound, not BW-bound). Also writes h[0] = h0 (absorbs the memcpy).
__global__ __launch_bounds__(256) void scan_phase2_kernel(
    const float* __restrict__ P, const float* __restrict__ Q,
    const float* __restrict__ h0,   // [NCH]
    float* __restrict__ Hc,         // [CHUNKS][NCH] = h at chunk start
    float* __restrict__ hbase) {    // h[0] region
    const int ch = blockIdx.x * 256 + threadIdx.x;  // 0..NCH-1
    float h = h0[ch];
    hbase[ch] = h;
#pragma unroll 8
    for (int c = 0; c < CHUNKS; ++c) {
        Hc[(size_t)c * NCH + ch] = h;
        h = P[(size_t)c * NCH + ch] * h + Q[(size_t)c * NCH + ch];
    }
}

// Phase 3: replay chunk with correct incoming h; in-place overwrite:
// alpha region -> output, v region -> h[t+1].
__global__ __launch_bounds__(256) void scan_phase3_kernel(
    float4* __restrict__ alpha_out,  // in: alpha[t], out: output[t]
    float4* __restrict__ v_h,        // in: v[t] (at h[t+1] slot), out: h[t+1]
    const float4* __restrict__ Hc) {
    const int j4 = blockIdx.x * 256 + threadIdx.x;
    const int c = blockIdx.y;
    float4 h = Hc[(size_t)c * NCH4 + j4];
    size_t base = (size_t)c * CHUNK_LEN * NCH4 + j4;
#pragma unroll 4
    for (int t = 0; t < CHUNK_LEN; ++t) {
        float4 a = alpha_out[base + (size_t)t * NCH4];
        float4 vv = v_h[base + (size_t)t * NCH4];
        h.x = a.x * h.x + (1.f - a.x) * vv.x;
        h.y = a.y * h.y + (1.f - a.y) * vv.y;
        h.z = a.z * h.z + (1.f - a.z) * vv.z;
        h.w = a.w * h.w + (1.f - a.w) * vv.w;
        float4 o;
        o.x = h.x * h.x * sigmoidf(h.x);
        o.y = h.y * h.y * sigmoidf(h.y);
        o.z = h.z * h.z * sigmoidf(h.z);
        o.w = h.w * h.w * sigmoidf(h.w);
        alpha_out[base + (size_t)t * NCH4] = o;
        v_h[base + (size_t)t * NCH4] = h;
    }
}

extern "C" void kernel_launch(void* const* d_in, const int* in_sizes, int n_in,
                              void* d_out, int out_size, void* d_ws, size_t ws_size,
                              hipStream_t stream) {
    const float* x  = (const float*)d_in[0];   // [T,B,D]
    const float* h0 = (const float*)d_in[1];   // [B,D]
    const float* Wa = (const float*)d_in[2];   // [D,D]
    const float* ba = (const float*)d_in[3];   // [D]
    const float* Wv = (const float*)d_in[4];   // [D,D]
    const float* bv = (const float*)d_in[5];   // [D]

    float* out = (float*)d_out;                       // output region [T][NCH]
    float* hbase = out + (size_t)T_DIM * NCH;         // h region [T+1][NCH]
    float* alpha = out;                               // temp alpha in output region
    float* vbuf = hbase + NCH;                        // temp v in h[1..T]

    char* ws = (char*)d_ws;
    unsigned short* xb   = (unsigned short*)ws;                      // 32 MB
    unsigned short* Wcat = (unsigned short*)(ws + 33554432);         // 4 MB
    float* P  = (float*)(ws + 37748736);                             // 2 MB
    float* Q  = (float*)(ws + 39845888);                             // 2 MB
    float* Hc = (float*)(ws + 41943040);                             // 2 MB

    // one-time: allow 128 KiB dynamic LDS for the GEMM
    static bool attr_done = false;
    if (!attr_done) {
        hipFuncSetAttribute(reinterpret_cast<const void*>(gemm_fused_kernel),
                            hipFuncAttributeMaxDynamicSharedMemorySize, 131072);
        attr_done = true;
    }

    // 1. convert all inputs to bf16 (single launch)
    const int nconv = (M_DIM * K_DIM / 4) + (2 * D_DIM * D_DIM / 4);  // 4718592
    convert_all_kernel<<<nconv / 256, 256, 0, stream>>>(
        (const float4*)x, (const float4*)Wa, (const float4*)Wv,
        (ushort4*)xb, (ushort4*)Wcat);

    // 2. fused GEMM: alpha = sigmoid(x Wa^T + ba) -> output region
    //                v     =         x Wv^T + bv  -> h[1..T] region
    gemm_fused_kernel<<<512, 512, 131072, stream>>>(xb, Wcat, ba, bv, alpha, vbuf);

    // 3. chunked scan (phase2 also writes h[0] = h0)
    dim3 sgrid(NCH4 / 256, CHUNKS);
    scan_phase1_kernel<<<sgrid, 256, 0, stream>>>(
        (const float4*)alpha, (const float4*)vbuf, (float4*)P, (float4*)Q);
    scan_phase2_kernel<<<NCH / 256, 256, 0, stream>>>(
        P, Q, h0, Hc, hbase);
    scan_phase3_kernel<<<sgrid, 256, 0, stream>>>(
        (float4*)alpha, (float4*)vbuf, (const float4*)Hc);
}

// Round 3
// 315.764 us; speedup vs baseline: 1.0930x; 1.0158x over previous
//
#include <hip/hip_runtime.h>
#include <hip/hip_bf16.h>

// Problem constants
#define T_DIM 2048
#define B_DIM 8
#define D_DIM 1024
#define M_DIM (T_DIM * B_DIM)     // 16384
#define K_DIM D_DIM               // 1024
#define NW_DIM (2 * D_DIM)        // 2048 combined GEMM cols (alpha | v)
#define NCH (B_DIM * D_DIM)       // 8192 channels
#define NCH4 (NCH / 4)            // 2048 float4 channels
#define CHUNKS 64
#define CHUNK_LEN 32              // 64*32 = 2048 = T

typedef __attribute__((ext_vector_type(8))) short bf16x8;
typedef __attribute__((ext_vector_type(4))) float f32x4;

__device__ __forceinline__ unsigned short bf16_rne(float f) {
    unsigned u = __float_as_uint(f);
    unsigned r = u + 0x7fffu + ((u >> 16) & 1u);
    return (unsigned short)(r >> 16);
}

__device__ __forceinline__ float sigmoidf(float z) {
    return 1.0f / (1.0f + __expf(-z));
}

__device__ __forceinline__ void load_lds16(const void* g, void* l) {
    __builtin_amdgcn_global_load_lds(
        (const __attribute__((address_space(1))) void*)g,
        (__attribute__((address_space(3))) void*)l,
        16, 0, 0);
}

// ---------------- fused input conversion: x, Wa, Wv -> bf16 ----------------
__global__ __launch_bounds__(256) void convert_all_kernel(
    const float4* __restrict__ x,
    const float4* __restrict__ Wa,
    const float4* __restrict__ Wv,
    ushort4* __restrict__ xb,
    ushort4* __restrict__ Wcat) {
    const int nx4 = M_DIM * K_DIM / 4;       // 4194304
    const int half4 = D_DIM * D_DIM / 4;     // 262144
    int i = blockIdx.x * 256 + threadIdx.x;
    float4 f;
    ushort4* __restrict__ dst;
    int di;
    if (i < nx4) {
        f = x[i];
        dst = xb;
        di = i;
    } else {
        int j = i - nx4;
        f = (j < half4) ? Wa[j] : Wv[j - half4];
        dst = Wcat;
        di = j;
    }
    ushort4 o;
    o.x = bf16_rne(f.x);
    o.y = bf16_rne(f.y);
    o.z = bf16_rne(f.z);
    o.w = bf16_rne(f.w);
    dst[di] = o;
}

// ---------------- fused bf16 MFMA GEMM, 128x256 tile, 2 blocks/CU --------
// A: [M,K] bf16 row-major.  Wcat: [2048,1024] bf16 row-major (B^T layout).
// cols [0,1024): alpha = sigmoid(xWa^T + ba) -> alpha_dst
// cols [1024,2048): v = xWv^T + bv -> v_dst. Both dsts row stride 1024.
//
// R2 theory: prior 256x256/8-wave config had acc[8][4]=128 regs/thread
// (AGPR) + ~112 VGPR => ~240 combined => 2 waves/SIMD, 1 block/CU, two
// serial block generations, epilogue fully exposed. This config targets
// OCCUPANCY: wave tile 64x64 (acc=64 regs), combined ~120 <= 128 =>
// 4 waves/SIMD via __launch_bounds__(512,4); ring-3 of BK=32 buffers
// (72 KiB) => 2 blocks/CU. Cross-block TLP hides staging drains and
// epilogue writes.
//  - 1024 blocks (128 M-tiles x 8 N-tiles), bijective XCD swizzle.
//  - Depth-2 prefetch: stage tile t+2 while computing t; steady vmcnt(3)
//    (3 loads/wave/tile) retires t+1's loads, leaves t+2's in flight.
//  - ONE barrier per K-tile (end). Ring-3 WAR on buf (t+2)%3 == (t-1)%3 is
//    closed by tile t-1's end barrier (reads precede each wave's lgkmcnt(0)).
//  - LDS XOR swizzle (verified, 0 conflicts): 128 B physical rows hold 2
//    tile rows; 16B-block perm p = (((r&1)<<2)|q) ^ ((r>>1)&7); inverse
//    perm applied to the GLOBAL source (gload_lds dest stays linear).
__global__ __launch_bounds__(512, 4) void gemm_fused_kernel(
    const unsigned short* __restrict__ A,
    const unsigned short* __restrict__ W,
    const float* __restrict__ ba,
    const float* __restrict__ bv,
    float* __restrict__ alpha_dst,
    float* __restrict__ v_dst) {
    extern __shared__ __attribute__((aligned(16))) char smem[];  // 3*24576

    const int tid = threadIdx.x;
    const int lane = tid & 63;
    const int w = tid >> 6;          // wave 0..7
    const int wm = w >> 2;           // wave row (0..1) -> 64 rows each
    const int wn = w & 3;            // wave col (0..3) -> 64 cols each
    const int quad = lane >> 4;      // 0..3
    const int l16 = lane & 15;

    // XCD-aware bijective swizzle: nwg=1024, 128 blocks per XCD chunk.
    // Within a chunk, 8 consecutive blocks share one A-panel (all 8 N-tiles)
    // -> L2 temporal locality on A.
    const int bid = blockIdx.x;
    const int swz = (bid & 7) * 128 + (bid >> 3);
    const int bx = swz & 7;          // N tile (0..7)
    const int by = swz >> 3;         // M tile (0..127)
    const int bm = by * 128;
    const int bn = bx * 256;         // col in the 2048-wide space

    // --- fragment-read byte offsets (swizzled LDS) ---
    // logical (r,q): q = quad; A: r = wm*64 + i*16 + l16; B: r = wn*64 + ...
    // phys byte = (r>>1)*128 + ((((r&1)<<2)|q) ^ ((r>>1)&7))*16
    const int vsw = (((l16 & 1) << 2) | quad) ^ (l16 >> 1);
    const int rdA = wm * 4096 + (l16 >> 1) * 128 + vsw * 16;  // + i*1024
    const int rdB = wn * 4096 + (l16 >> 1) * 128 + vsw * 16;  // + j*1024

    // --- staging source offsets (inverse swizzle on global address) ---
    // Each gload_lds fills one 1 KiB span (16 tile rows, 8-phys-row aligned).
    // lane -> phys row lane>>3, block p=lane&7; logical v' = p ^ (lane>>3);
    // source row = base + 2*(lane>>3) + (v'>>2), col 16B-block = v'&3.
    const int hl = lane >> 3;            // 0..7
    const int vp = (lane & 7) ^ hl;
    const int qsrc = vp & 3;
    const int rb = (vp >> 2) & 1;
    const int rA  = 16 * w + 2 * hl + rb;        // A tile row 0..127
    const int rB0 = 32 * w + 2 * hl + rb;        // B tile row (grp 2w)
    const int rB1 = rB0 + 16;                    // B tile row (grp 2w+1)
    const char* Ab = (const char*)A;
    const char* Wb = (const char*)W;
    const size_t offA  = (size_t)(bm + rA ) * 2048 + (size_t)qsrc * 16;
    const size_t offB0 = (size_t)(bn + rB0) * 2048 + (size_t)qsrc * 16;
    const size_t offB1 = (size_t)(bn + rB1) * 2048 + (size_t)qsrc * 16;
    const int ldsA  = w * 1024;          // wave-uniform dests
    const int ldsB0 = (2 * w) * 1024;
    const int ldsB1 = (2 * w + 1) * 1024;

    f32x4 acc[4][4];
    {
        f32x4 zero = {0.f, 0.f, 0.f, 0.f};
#pragma unroll
        for (int i = 0; i < 4; ++i)
#pragma unroll
            for (int j = 0; j < 4; ++j) acc[i][j] = zero;
    }

    // stage K-tile t into ring buffer buf (A: 8 KiB, B: 16 KiB).
    auto stage = [&](int buf, int t) {
        char* bA = smem + buf * 24576;
        char* bB = bA + 8192;
        const size_t ko = (size_t)t * 64;
        load_lds16(Ab + offA + ko, bA + ldsA);
        load_lds16(Wb + offB0 + ko, bB + ldsB0);
        load_lds16(Wb + offB1 + ko, bB + ldsB1);
    };

    // one K-tile: 8 ds_read_b128 + optional stage(t+2) + 16 MFMA.
    auto tile_step = [&](int buf, int nbuf, int tn, bool do_stage, int vm,
                         bool bar) {
        const char* bA = smem + buf * 24576;
        const char* bB = bA + 8192;
        bf16x8 af[4], bfr[4];
#pragma unroll
        for (int i = 0; i < 4; ++i)
            af[i] = *(const bf16x8*)(bA + rdA + i * 1024);
#pragma unroll
        for (int j = 0; j < 4; ++j)
            bfr[j] = *(const bf16x8*)(bB + rdB + j * 1024);
        if (do_stage) stage(nbuf, tn);
        asm volatile("s_waitcnt lgkmcnt(0)" ::: "memory");
        __builtin_amdgcn_sched_barrier(0);
        __builtin_amdgcn_s_setprio(1);
#pragma unroll
        for (int i = 0; i < 4; ++i)
#pragma unroll
            for (int j = 0; j < 4; ++j)
                acc[i][j] = __builtin_amdgcn_mfma_f32_16x16x32_bf16(
                    af[i], bfr[j], acc[i][j], 0, 0, 0);
        __builtin_amdgcn_s_setprio(0);
        if (vm == 3) asm volatile("s_waitcnt vmcnt(3)" ::: "memory");
        else if (vm == 0) asm volatile("s_waitcnt vmcnt(0)" ::: "memory");
        if (bar) __builtin_amdgcn_s_barrier();
    };

    // prologue: stage tiles 0,1; wait tile 0 (vmcnt(3) leaves tile 1 in
    // flight); barrier.
    stage(0, 0);
    stage(1, 1);
    asm volatile("s_waitcnt vmcnt(3)" ::: "memory");
    __builtin_amdgcn_s_barrier();

    // 32 K-tiles (K=1024, BK=32); ring-3 unrolled. Tiles 0..29 stage t+2.
    for (int it = 0; it < 10; ++it) {
        const int t = it * 3;
        tile_step(0, 2, t + 2, true, 3, true);
        tile_step(1, 0, t + 3, true, 3, true);
        tile_step(2, 1, t + 4, true, 3, true);
    }
    tile_step(0, 0, 0, false, 0, true);    // tile 30; drain tile 31's loads
    tile_step(1, 0, 0, false, -1, false);  // tile 31; no wait/barrier

    // epilogue: C/D layout col = lane&15, row = quad*4 + reg.
    // bn multiples of 256 -> tile entirely alpha or v (block-uniform).
    const bool is_alpha = (bn < D_DIM);
    float* __restrict__ dst = is_alpha ? alpha_dst : v_dst;
    const float* __restrict__ bias = is_alpha ? ba : bv;
    const int nb = bn - (is_alpha ? 0 : D_DIM);
#pragma unroll
    for (int j = 0; j < 4; ++j) {
        const int n = nb + wn * 64 + j * 16 + l16;
        const float bias_n = bias[n];
#pragma unroll
        for (int i = 0; i < 4; ++i) {
            const int m0 = bm + wm * 64 + i * 16 + quad * 4;
#pragma unroll
            for (int r = 0; r < 4; ++r) {
                float val = acc[i][j][r] + bias_n;
                if (is_alpha) val = sigmoidf(val);
                dst[(size_t)(m0 + r) * D_DIM + n] = val;
            }
        }
    }
}

// ---------------- chunked parallel scan ----------------
// h_t = a_t*h_{t-1} + (1-a_t)*v_t  == affine h_out = P*h_in + Q per chunk.

// Phase 1: per (chunk, channel4) compute chunk composition (P,Q).
__global__ __launch_bounds__(256) void scan_phase1_kernel(
    const float4* __restrict__ alpha,  // [T][NCH4]
    const float4* __restrict__ v,      // [T][NCH4]
    float4* __restrict__ P,            // [CHUNKS][NCH4]
    float4* __restrict__ Q) {
    const int j4 = blockIdx.x * 256 + threadIdx.x;  // 0..NCH4-1
    const int c = blockIdx.y;
    float4 Pr = {1.f, 1.f, 1.f, 1.f};
    float4 Qr = {0.f, 0.f, 0.f, 0.f};
    size_t base = (size_t)c * CHUNK_LEN * NCH4 + j4;
#pragma unroll 4
    for (int t = 0; t < CHUNK_LEN; ++t) {
        float4 a = alpha[base + (size_t)t * NCH4];
        float4 vv = v[base + (size_t)t * NCH4];
        Pr.x *= a.x; Pr.y *= a.y; Pr.z *= a.z; Pr.w *= a.w;
        Qr.x = a.x * Qr.x + (1.f - a.x) * vv.x;
        Qr.y = a.y * Qr.y + (1.f - a.y) * vv.y;
        Qr.z = a.z * Qr.z + (1.f - a.z) * vv.z;
        Qr.w = a.w * Qr.w + (1.f - a.w) * vv.w;
    }
    P[(size_t)c * NCH4 + j4] = Pr;
    Q[(size_t)c * NCH4 + j4] = Qr;
}

// Phase 2: exclusive prefix over chunks. Scalar per channel: 8192 threads.
// Also writes h[0] = h0 (absorbs the memcpy).
__global__ __launch_bounds__(256) void scan_phase2_kernel(
    const float* __restrict__ P, const float* __restrict__ Q,
    const float* __restrict__ h0,   // [NCH]
    float* __restrict__ Hc,         // [CHUNKS][NCH] = h at chunk start
    float* __restrict__ hbase) {    // h[0] region
    const int ch = blockIdx.x * 256 + threadIdx.x;  // 0..NCH-1
    float h = h0[ch];
    hbase[ch] = h;
#pragma unroll 8
    for (int c = 0; c < CHUNKS; ++c) {
        Hc[(size_t)c * NCH + ch] = h;
        h = P[(size_t)c * NCH + ch] * h + Q[(size_t)c * NCH + ch];
    }
}

// Phase 3: replay chunk with correct incoming h; in-place overwrite:
// alpha region -> output, v region -> h[t+1].
__global__ __launch_bounds__(256) void scan_phase3_kernel(
    float4* __restrict__ alpha_out,  // in: alpha[t], out: output[t]
    float4* __restrict__ v_h,        // in: v[t] (at h[t+1] slot), out: h[t+1]
    const float4* __restrict__ Hc) {
    const int j4 = blockIdx.x * 256 + threadIdx.x;
    const int c = blockIdx.y;
    float4 h = Hc[(size_t)c * NCH4 + j4];
    size_t base = (size_t)c * CHUNK_LEN * NCH4 + j4;
#pragma unroll 4
    for (int t = 0; t < CHUNK_LEN; ++t) {
        float4 a = alpha_out[base + (size_t)t * NCH4];
        float4 vv = v_h[base + (size_t)t * NCH4];
        h.x = a.x * h.x + (1.f - a.x) * vv.x;
        h.y = a.y * h.y + (1.f - a.y) * vv.y;
        h.z = a.z * h.z + (1.f - a.z) * vv.z;
        h.w = a.w * h.w + (1.f - a.w) * vv.w;
        float4 o;
        o.x = h.x * h.x * sigmoidf(h.x);
        o.y = h.y * h.y * sigmoidf(h.y);
        o.z = h.z * h.z * sigmoidf(h.z);
        o.w = h.w * h.w * sigmoidf(h.w);
        alpha_out[base + (size_t)t * NCH4] = o;
        v_h[base + (size_t)t * NCH4] = h;
    }
}

extern "C" void kernel_launch(void* const* d_in, const int* in_sizes, int n_in,
                              void* d_out, int out_size, void* d_ws, size_t ws_size,
                              hipStream_t stream) {
    const float* x  = (const float*)d_in[0];   // [T,B,D]
    const float* h0 = (const float*)d_in[1];   // [B,D]
    const float* Wa = (const float*)d_in[2];   // [D,D]
    const float* ba = (const float*)d_in[3];   // [D]
    const float* Wv = (const float*)d_in[4];   // [D,D]
    const float* bv = (const float*)d_in[5];   // [D]

    float* out = (float*)d_out;                       // output region [T][NCH]
    float* hbase = out + (size_t)T_DIM * NCH;         // h region [T+1][NCH]
    float* alpha = out;                               // temp alpha in output region
    float* vbuf = hbase + NCH;                        // temp v in h[1..T]

    char* ws = (char*)d_ws;
    unsigned short* xb   = (unsigned short*)ws;                      // 32 MB
    unsigned short* Wcat = (unsigned short*)(ws + 33554432);         // 4 MB
    float* P  = (float*)(ws + 37748736);                             // 2 MB
    float* Q  = (float*)(ws + 39845888);                             // 2 MB
    float* Hc = (float*)(ws + 41943040);                             // 2 MB

    // one-time: allow 72 KiB dynamic LDS for the GEMM
    static bool attr_done = false;
    if (!attr_done) {
        hipFuncSetAttribute(reinterpret_cast<const void*>(gemm_fused_kernel),
                            hipFuncAttributeMaxDynamicSharedMemorySize, 73728);
        attr_done = true;
    }

    // 1. convert all inputs to bf16 (single launch)
    const int nconv = (M_DIM * K_DIM / 4) + (2 * D_DIM * D_DIM / 4);  // 4718592
    convert_all_kernel<<<nconv / 256, 256, 0, stream>>>(
        (const float4*)x, (const float4*)Wa, (const float4*)Wv,
        (ushort4*)xb, (ushort4*)Wcat);

    // 2. fused GEMM: alpha = sigmoid(x Wa^T + ba) -> output region
    //                v     =         x Wv^T + bv  -> h[1..T] region
    gemm_fused_kernel<<<1024, 512, 73728, stream>>>(xb, Wcat, ba, bv, alpha,
                                                    vbuf);

    // 3. chunked scan (phase2 also writes h[0] = h0)
    dim3 sgrid(NCH4 / 256, CHUNKS);
    scan_phase1_kernel<<<sgrid, 256, 0, stream>>>(
        (const float4*)alpha, (const float4*)vbuf, (float4*)P, (float4*)Q);
    scan_phase2_kernel<<<NCH / 256, 256, 0, stream>>>(
        P, Q, h0, Hc, hbase);
    scan_phase3_kernel<<<sgrid, 256, 0, stream>>>(
        (float4*)alpha, (float4*)vbuf, (const float4*)Hc);
}